// Round 3
// baseline (3446.775 us; speedup 1.0000x reference)
//
#include <hip/hip_runtime.h>
#include <hip/hip_bf16.h>

// NRDE layer (all I/O fp32):
//   A2[a][b][:] = [ A[h*256+w] = sum_d ml_w[w,h*136+d]*logsig[b,a,1+d] | bias[h] = sum_d ml_b[h*136+d]*logsig ]
//   (one big MFMA GEMM, M=8192 (a,b), N=32896 (h*256+w plus 128 bias cols), K=136->160)
//   scan: 1 block per batch element b, 64 RK2 steps; MLP weights live in REGISTERS (bf16 packed).
// times = arange => k1 of step n uses coeff idx max(n-1,0), k2 uses idx n; dt read from times.

#define BB 128
#define SS 64
#define LL 137
#define HH 128
#define DIN 64
#define WW 256
#define DD 136
#define KP 160              // K padded for MFMA
#define NC 32768            // h*256+w columns
#define NCR 32896           // + 128 bias columns
#define BST 168             // b_sm col stride (shorts)
#define OUT2_OFF ((size_t)BB*(SS+1)*HH)

typedef __hip_bfloat16 bf16;
typedef __attribute__((ext_vector_type(8))) short short8;
typedef __attribute__((ext_vector_type(4))) float f32x4;

__device__ __forceinline__ float bf2f(bf16 x) { return __bfloat162float(x); }
__device__ __forceinline__ bf16  f2bf(float x){ return __float2bfloat16(x); }
__device__ __forceinline__ float2 upk(unsigned u){
  float2 r;
  r.x = __uint_as_float(u << 16);
  r.y = __uint_as_float(u & 0xffff0000u);
  return r;
}
__device__ __forceinline__ unsigned pk2(float a, float b){
  bf16 lo = f2bf(a), hi = f2bf(b);
  return (unsigned)*(unsigned short*)&lo | ((unsigned)*(unsigned short*)&hi << 16);
}

// ---------------- prep: coeff rows m=a*128+b (fp32 -> bf16), K padded ----------------
__global__ void prep_coeff(const float* __restrict__ logsig, bf16* __restrict__ cA){
  int m = blockIdx.x, d = threadIdx.x;
  int a = m >> 7, b = m & 127;
  float v = 0.0f;
  if (d < DD) v = logsig[(size_t)(b*SS + a)*LL + 1 + d];
  cA[(size_t)m*KP + d] = f2bf(v);
}

// ---------------- prep: btt2[c][d]; c<NC: ml_w[w][h*136+d] (c=h*256+w); c>=NC: ml_b[(c-NC)*136+d] ----------------
__global__ void prep_btt(const float* __restrict__ mlw, const float* __restrict__ mlb,
                         bf16* __restrict__ btt){
  int c = blockIdx.x, d = threadIdx.x;
  float v = 0.0f;
  if (d < DD){
    if (c < NC){
      int h = c >> 8, w = c & 255;
      v = mlw[(size_t)w*(HH*DD) + h*DD + d];
    } else {
      v = mlb[(size_t)(c - NC)*DD + d];
    }
  }
  btt[(size_t)c*KP + d] = f2bf(v);
}

// ---------------- A-GEMM: 128x128 tiles, B staged once per block, 8 m-tiles per block ----------------
// 512 threads = 8 waves: wave w -> rows (w&3)*32 (2 frags), cols (w>>2)*64 (4 frags).
__global__ __launch_bounds__(512, 4) void agemm_kernel(const bf16* __restrict__ cA,
                                                       const bf16* __restrict__ btt,
                                                       bf16* __restrict__ As,
                                                       int mAbs0, int cc){
  __shared__ __align__(16) short b_sm[128*BST];   // 43008 B, all 160 k
  __shared__ __align__(16) short ao_sm[128*136];  // 34816 B, aliased: A-tile (stride 40) / out tile
  const int t = threadIdx.x, lane = t & 63, wid = t >> 6;
  const int nt = blockIdx.y;
  const int c0 = nt*128;
  const int mW = (wid & 3)*32, cW = (wid >> 2)*64;
  const int mr = lane & 15, q = lane >> 4;

  // stage B once: 128 cols x 160 d
  #pragma unroll
  for (int rep = 0; rep < 5; ++rep){
    int col = t >> 2, seg = (t & 3) + rep*4;   // seg 0..19
    uint4 v = *(const uint4*)(btt + (size_t)(c0+col)*KP + seg*8);
    *(uint4*)&b_sm[col*BST + seg*8] = v;
  }

  for (int mt = 0; mt < 8; ++mt){
    int mTile = blockIdx.x*8 + mt;
    if (mTile >= cc) break;
    int mBase = mTile*128;              // local row base (chunk)
    int mAbs  = mAbs0 + mBase;          // absolute row base into cA

    f32x4 acc[2][4];
    #pragma unroll
    for (int i = 0; i < 2; ++i)
      #pragma unroll
      for (int j = 0; j < 4; ++j)
        acc[i][j] = (f32x4){0.f,0.f,0.f,0.f};

    __syncthreads();   // protect ao_sm (epilogue reads of prev tile done; B already staged)
    #pragma unroll
    for (int kk = 0; kk < 5; ++kk){
      int d0 = kk*32;
      { // stage A: 128 rows x 32 d = 512 x 16B
        int row = t >> 2, seg = t & 3;
        uint4 v = *(const uint4*)(cA + (size_t)(mAbs+row)*KP + d0 + seg*8);
        *(uint4*)&ao_sm[row*40 + seg*8] = v;
      }
      __syncthreads();
      short8 af[2], bfr[4];
      #pragma unroll
      for (int mi = 0; mi < 2; ++mi) af[mi]  = *(const short8*)&ao_sm[(mW + mi*16 + mr)*40 + q*8];
      #pragma unroll
      for (int ci = 0; ci < 4; ++ci) bfr[ci] = *(const short8*)&b_sm[(cW + ci*16 + mr)*BST + d0 + q*8];
      #pragma unroll
      for (int mi = 0; mi < 2; ++mi)
        #pragma unroll
        for (int ci = 0; ci < 4; ++ci)
          acc[mi][ci] = __builtin_amdgcn_mfma_f32_16x16x32_bf16(af[mi], bfr[ci], acc[mi][ci], 0, 0, 0);
      __syncthreads();
    }

    // epilogue: regs -> LDS bf16 -> 16B global stores
    #pragma unroll
    for (int mi = 0; mi < 2; ++mi)
      #pragma unroll
      for (int ci = 0; ci < 4; ++ci){
        int col = cW + ci*16 + mr;
        #pragma unroll
        for (int r = 0; r < 4; ++r){
          int row = mW + mi*16 + q*4 + r;
          bf16 bv = f2bf(acc[mi][ci][r]);
          ao_sm[row*136 + col] = *(short*)&bv;
        }
      }
    __syncthreads();
    #pragma unroll
    for (int rep = 0; rep < 4; ++rep){
      int idx = t + rep*512;
      int row = idx >> 4, seg = idx & 15;
      uint4 v = *(const uint4*)&ao_sm[row*136 + seg*8];
      *(uint4*)(As + (size_t)(mBase + row)*NCR + c0 + seg*8) = v;
    }
  }
}

// ---------------- scan: 1 block / batch element, 512 threads, weights in registers ----------------
__global__ __launch_bounds__(512, 2) void scan_kernel(
    const float* __restrict__ times, const float* __restrict__ initial,
    const float* __restrict__ in_w, const float* __restrict__ in_b,
    const float* __restrict__ h1_w, const float* __restrict__ h1_b,
    const float* __restrict__ h2_w, const float* __restrict__ h2_b,
    const float* __restrict__ vo_w, const float* __restrict__ vo_b,
    const bf16* __restrict__ As,
    float* __restrict__ y_state, float* __restrict__ out,
    int s0, int s1, int aBase)
{
  const int b = blockIdx.x, t = threadIdx.x;
  const int j = t & 255, half = t >> 8;          // col, K-half
  const int hh = t & 127, q4 = t >> 7;           // matvec: h, w-quarter
  __shared__ __align__(16) float yv[HH], ytmp[HH], bufA[WW], bufB[WW], kk1[HH], kk2[HH];
  __shared__ __align__(16) float part[512];

  // ---- load weights into registers (bf16 packed along K) ----
  unsigned w1p[32], w2p[64], w3p[64];
  {
    const float* w = h1_w + (size_t)(half*64)*WW + j;
    #pragma unroll
    for (int i = 0; i < 32; ++i)
      w1p[i] = pk2(w[(size_t)(2*i)*WW], w[(size_t)(2*i+1)*WW]);
  }
  {
    const float* w = h2_w + (size_t)(half*128)*WW + j;
    #pragma unroll
    for (int i = 0; i < 64; ++i)
      w2p[i] = pk2(w[(size_t)(2*i)*WW], w[(size_t)(2*i+1)*WW]);
  }
  {
    const float* w = vo_w + (size_t)(half*128)*WW + j;
    #pragma unroll
    for (int i = 0; i < 64; ++i)
      w3p[i] = pk2(w[(size_t)(2*i)*WW], w[(size_t)(2*i+1)*WW]);
  }
  const float b1 = h1_b[j], b2 = h2_b[j], b3 = vo_b[j];

  if (s0 == 0){
    if (t < HH){
      float acc = in_b[t];
      for (int i = 0; i < DIN; ++i)
        acc += initial[b*DIN + i] * in_w[(size_t)i*HH + t];
      yv[t] = acc;
      out[((size_t)b*(SS+1))*HH + t] = acc;
    }
  } else {
    if (t < HH) yv[t] = y_state[b*HH + t];
  }
  __syncthreads();

  for (int n = s0; n < s1; ++n){
    float t0 = times[n], t1 = times[n+1];
    float dt = t1 - t0;
    int idx1 = (n >= 1) ? n : 1;
    float inv1 = 1.f/(times[idx1] - times[idx1-1]);
    float inv2 = 1.f/dt;
    int a1 = ((n >= 1) ? (n-1) : 0) - aBase;
    int a2 = n - aBase;

    #pragma unroll
    for (int ev = 0; ev < 2; ++ev){
      const float* yin = (ev == 0) ? yv : ytmp;
      int aLoc = (ev == 0) ? a1 : a2;
      float inv_dtf = (ev == 0) ? inv1 : inv2;
      float* kout = (ev == 0) ? kk1 : kk2;

      // prefetch A row + bias (independent of MLP)
      uint4 Au[8];
      const bf16* Arow = As + (((size_t)aLoc*BB + b)*NCR) + hh*WW + q4*64;
      #pragma unroll
      for (int i = 0; i < 8; ++i) Au[i] = *(const uint4*)(Arow + i*8);
      float biasv = 0.f;
      if (t < HH){
        bf16 bb = As[(((size_t)aLoc*BB + b)*NCR) + NC + t];
        biasv = bf2f(bb);
      }

      // L1: 128 -> 256 relu
      {
        float acc = 0.f;
        const float4* y4 = (const float4*)(yin + half*64);
        #pragma unroll
        for (int i = 0; i < 16; ++i){
          float4 f = y4[i];
          float2 p0 = upk(w1p[2*i]), p1 = upk(w1p[2*i+1]);
          acc += f.x*p0.x + f.y*p0.y + f.z*p1.x + f.w*p1.y;
        }
        part[t] = acc;
      }
      __syncthreads();
      if (t < WW){
        float v = b1 + part[t] + part[t+256];
        bufA[t] = v > 0.f ? v : 0.f;
      }
      __syncthreads();
      // L2: 256 -> 256 relu
      {
        float acc = 0.f;
        const float4* x4 = (const float4*)(bufA + half*128);
        #pragma unroll
        for (int i = 0; i < 32; ++i){
          float4 f = x4[i];
          float2 p0 = upk(w2p[2*i]), p1 = upk(w2p[2*i+1]);
          acc += f.x*p0.x + f.y*p0.y + f.z*p1.x + f.w*p1.y;
        }
        part[t] = acc;
      }
      __syncthreads();
      if (t < WW){
        float v = b2 + part[t] + part[t+256];
        bufB[t] = v > 0.f ? v : 0.f;
      }
      __syncthreads();
      // L3: 256 -> 256 tanh
      {
        float acc = 0.f;
        const float4* x4 = (const float4*)(bufB + half*128);
        #pragma unroll
        for (int i = 0; i < 32; ++i){
          float4 f = x4[i];
          float2 p0 = upk(w3p[2*i]), p1 = upk(w3p[2*i+1]);
          acc += f.x*p0.x + f.y*p0.y + f.z*p1.x + f.w*p1.y;
        }
        part[t] = acc;
      }
      __syncthreads();
      if (t < WW){
        float v = b3 + part[t] + part[t+256];
        bufA[t] = tanhf(v);
      }
      __syncthreads();
      // matvec: k[h] = (sum_w h3[w]*A[h][w] + bias)/dtf
      {
        const float* hv = bufA + q4*64;
        float s = 0.f;
        #pragma unroll
        for (int w8 = 0; w8 < 8; ++w8){
          uint4 u = Au[w8];
          float2 p;
          p = upk(u.x); s += hv[w8*8+0]*p.x + hv[w8*8+1]*p.y;
          p = upk(u.y); s += hv[w8*8+2]*p.x + hv[w8*8+3]*p.y;
          p = upk(u.z); s += hv[w8*8+4]*p.x + hv[w8*8+5]*p.y;
          p = upk(u.w); s += hv[w8*8+6]*p.x + hv[w8*8+7]*p.y;
        }
        part[t] = s;
      }
      __syncthreads();
      if (t < HH)
        kout[t] = (part[t] + part[t+128] + part[t+256] + part[t+384] + biasv) * inv_dtf;
      __syncthreads();
      if (ev == 0){
        if (t < HH) ytmp[t] = yv[t] + dt*kk1[t];
        __syncthreads();
      }
    }

    if (t < HH){
      float ynew = yv[t] + 0.5f*dt*(kk1[t] + kk2[t]);
      yv[t] = ynew;
      out[((size_t)b*(SS+1) + (n+1))*HH + t] = ynew;
    }
    __syncthreads();
  }

  if (t < HH){
    y_state[b*HH + t] = yv[t];
    if (s1 == SS) out[OUT2_OFF + (size_t)b*HH + t] = yv[t];
  }
}

extern "C" void kernel_launch(void* const* d_in, const int* in_sizes, int n_in,
                              void* d_out, int out_size, void* d_ws, size_t ws_size,
                              hipStream_t stream)
{
  (void)in_sizes; (void)n_in; (void)out_size;
  const float* times   = (const float*)d_in[0];
  const float* logsig  = (const float*)d_in[1];
  const float* initial = (const float*)d_in[2];
  const float* in_w    = (const float*)d_in[3];
  const float* in_b    = (const float*)d_in[4];
  const float* h1_w    = (const float*)d_in[5];
  const float* h1_b    = (const float*)d_in[6];
  const float* h2_w    = (const float*)d_in[7];
  const float* h2_b    = (const float*)d_in[8];
  const float* vo_w    = (const float*)d_in[9];
  const float* vo_b    = (const float*)d_in[10];
  const float* ml_w    = (const float*)d_in[11];
  const float* ml_b    = (const float*)d_in[12];
  float* out = (float*)d_out;

  char* ws = (char*)d_ws;
  size_t off = 0;
  bf16* cA      = (bf16*)(ws + off); off += (size_t)8192*KP*2;        // 2.62 MB
  bf16* btt     = (bf16*)(ws + off); off += (size_t)NCR*KP*2;         // 10.53 MB
  float* y_state= (float*)(ws + off); off += (size_t)BB*HH*4;         // 64 KB
  bf16* As      = (bf16*)(ws + off);
  size_t perA = (size_t)BB*NCR*2;                                     // 8.42 MB per a-index
  size_t avail = (ws_size > off) ? (ws_size - off) : 0;
  int C = (int)(avail / perA);
  if (C > SS) C = SS;
  if (C < 2) return;

  prep_coeff<<<8192, 160, 0, stream>>>(logsig, cA);
  prep_btt<<<NCR, 160, 0, stream>>>(ml_w, ml_b, btt);

  int s = 0, aB = 0;
  while (s < SS){
    int cc = SS - aB; if (cc > C) cc = C;
    agemm_kernel<<<dim3((cc+7)/8, 257), 512, 0, stream>>>(cA, btt, As, aB*BB, cc);
    int sEnd = aB + cc; if (sEnd > SS) sEnd = SS;
    scan_kernel<<<BB, 512, 0, stream>>>(times, initial, in_w, in_b, h1_w, h1_b,
        h2_w, h2_b, vo_w, vo_b, As, y_state, out, s, sEnd, aB);
    s = sEnd;
    aB = sEnd - 1;
  }
}